// Round 13
// baseline (41.957 us; speedup 1.0000x reference)
//
#include <hip/hip_runtime.h>

#define S_DIM 4096
#define B_DIM 8
#define LN_EPS 1e-3f

typedef _Float16 half8 __attribute__((ext_vector_type(8)));
typedef _Float16 half2v __attribute__((ext_vector_type(2)));
typedef float f32x4 __attribute__((ext_vector_type(4)));

// ---------------------------------------------------------------------------
// Dispatch 1: blocks 0..1023 = prep (fragment-contiguous wt2),
//   blocks 1024..1535 = banded stage1 (known-good, absmax-validated).
// wt2: flat idx = ((a*8 + j)*64 + l)*8 + e  holds W[k][a][c],
//   k=(j>>1)*16+(l&15), c=(j&1)*32+(l>>4)*8+e.  (1KB coalesced per fragment)
// ---------------------------------------------------------------------------
__global__ __launch_bounds__(256) void prep_stage1(const float* __restrict__ x,
                                                   const float* __restrict__ W,
                                                   _Float16* __restrict__ wt2,
                                                   _Float16* __restrict__ s_out) {
    if (blockIdx.x < 1024) {   // ---- prep role ----
        int idx = blockIdx.x * 256 + threadIdx.x;
        int a = idx >> 12;
        int j = (idx >> 9) & 7;
        int l2 = (idx >> 3) & 63;
        int e = idx & 7;
        int k = (j >> 1) * 16 + (l2 & 15);
        int c = (j & 1) * 32 + (l2 >> 4) * 8 + e;
        wt2[idx] = (_Float16)W[((k << 6) + a) * 64 + c];
        return;
    }
    // ---- stage1 role: banded s_pre (d <= 128..192) ----
    const int lin = blockIdx.x - 1024;
    const int it = lin & 63;
    const int by = lin >> 6;
    const int i0 = it * 64;
    const int tid = threadIdx.x;
    const int w = tid >> 6, l = tid & 63, lg = l >> 4, lr = l & 15;

    __shared__ _Float16 Bs[64 * 72];

    f32x4 acc[4] = {};
    const float iRowF = (float)(i0 + w * 16 + lr);
    const int ldC = tid & 63;
    const int ldJ = (tid >> 6) * 16;

    const int jt0 = (it >= 2) ? (it - 2) : 0;
    for (int jt = jt0; jt <= it; ++jt) {
        const int j0 = jt * 64;
        __syncthreads();
        {
            const float* xp = x + ((size_t)by * S_DIM + j0 + ldJ) * 64 + ldC;
            half8 v0, v1;
            #pragma unroll
            for (int q = 0; q < 8; ++q) {
                v0[q] = (_Float16)xp[q * 64];
                v1[q] = (_Float16)xp[(8 + q) * 64];
            }
            *(half8*)&Bs[ldC * 72 + ldJ] = v0;
            *(half8*)&Bs[ldC * 72 + ldJ + 8] = v1;
        }
        __syncthreads();
        #pragma unroll
        for (int kk = 0; kk < 2; ++kk) {
            half8 af;
            #pragma unroll
            for (int bq = 0; bq < 8; ++bq) {
                int j = j0 + kk * 32 + lg * 8 + bq;
                float df = iRowF - (float)j;
                float tv = (df > 0.f) ? __builtin_amdgcn_rcpf(df * df) : 0.f;
                af[bq] = (_Float16)tv;
            }
            #pragma unroll
            for (int nt = 0; nt < 4; ++nt) {
                half8 bf = *(const half8*)&Bs[(nt * 16 + lr) * 72 + kk * 32 + lg * 8];
                acc[nt] = __builtin_amdgcn_mfma_f32_16x16x32_f16(af, bf, acc[nt], 0, 0, 0);
            }
        }
    }

    #pragma unroll
    for (int nt = 0; nt < 4; ++nt)
        #pragma unroll
        for (int r = 0; r < 4; ++r)
            s_out[((size_t)by * S_DIM + i0 + w * 16 + lg * 4 + r) * 64 + nt * 16 + lr]
                = (_Float16)acc[nt][r];
}

// ---------------------------------------------------------------------------
// Stage 2 v11: OCCUPANCY build. 1024 thr = 16 waves = 2 row-groups x K-split 8.
//   64 rows/block (rg-half 32 rows, R=2 tiles/wave), acc=32 VGPR, all operands
//   in registers, W streams L2->VGPR (half-cluster ping-pong, 32 VGPR).
//   Total <=128 VGPR -> 4 waves/SIMD; barrier-free K-loop; TLP hides L2.
//   LDS only for epilogue partials (14 x 4KB f16).
// ---------------------------------------------------------------------------
__global__ __launch_bounds__(1024, 4) void stage2(const float* __restrict__ x,
                                                  const _Float16* __restrict__ s,
                                                  const _Float16* __restrict__ wt2,
                                                  const float* __restrict__ gamma,
                                                  const float* __restrict__ beta,
                                                  float* __restrict__ out) {
    const int r0 = blockIdx.x * 64;
    const int tid = threadIdx.x;
    const int w = tid >> 6, l = tid & 63, lg = l >> 4, lr = l & 15;
    const int rg = w & 1;          // row half: rows [r0 + rg*32, +32)
    const int ah = w >> 1;         // K-split: a = ah*8 + t, t in 0..7
    const int rbase = r0 + rg * 32;

    __shared__ __align__(16) half2v Pf[14336];   // 14 partial bufs x 4KB = 57KB

    // this wave's W stream: 8 slices x 8KB, lane-sliced by l*16
    const char* mylane = (const char*)wt2 + ((size_t)ah << 16) + l * 16;

    // permanent register operands: sf (16), xav (8)
    half8 sf[2][2];
    half8 xav[2];
    #pragma unroll
    for (int rt = 0; rt < 2; ++rt) {
        const size_t row = (size_t)(rbase + rt * 16 + lr);
        sf[rt][0] = *(const half8*)&s[row * 64 + lg * 8];
        sf[rt][1] = *(const half8*)&s[row * 64 + 32 + lg * 8];
        const float* xp = x + row * 64 + ah * 8;
        float4 v0 = *(const float4*)xp;
        float4 v1 = *(const float4*)(xp + 4);
        half8 h;
        h[0] = (_Float16)v0.x; h[1] = (_Float16)v0.y;
        h[2] = (_Float16)v0.z; h[3] = (_Float16)v0.w;
        h[4] = (_Float16)v1.x; h[5] = (_Float16)v1.y;
        h[6] = (_Float16)v1.z; h[7] = (_Float16)v1.w;
        xav[rt] = h;
    }

    f32x4 acc[2][4] = {};
    half8 WA[4], WB[4];
    half8 af[2][2];

    // half-step i: slice t=i>>1, col-half h=i&1 (frags j2 = 4h..4h+3, 4KB)
#define PREFH(BUF, i_)                                                         \
    {                                                                          \
        _Pragma("unroll")                                                      \
        for (int f_ = 0; f_ < 4; ++f_)                                         \
            BUF[f_] = *(const half8*)(mylane + (size_t)((i_) >> 1) * 8192 +    \
                                      (((i_) & 1) * 4 + f_) * 1024);           \
    }
#define COMPUTEH(CB, i_)                                                       \
    {                                                                          \
        if (((i_) & 1) == 0) {                                                 \
            _Pragma("unroll")                                                  \
            for (int rt_ = 0; rt_ < 2; ++rt_) {                                \
                _Float16 xa_ = xav[rt_][(i_) >> 1];                            \
                af[rt_][0] = sf[rt_][0] * xa_;                                 \
                af[rt_][1] = sf[rt_][1] * xa_;                                 \
            }                                                                  \
        }                                                                      \
        _Pragma("unroll")                                                      \
        for (int rt_ = 0; rt_ < 2; ++rt_)                                      \
            _Pragma("unroll")                                                  \
            for (int ntl_ = 0; ntl_ < 2; ++ntl_) {                             \
                const int nt_ = ((i_) & 1) * 2 + ntl_;                         \
                acc[rt_][nt_] = __builtin_amdgcn_mfma_f32_16x16x32_f16(        \
                    af[rt_][0], CB[ntl_ * 2 + 0], acc[rt_][nt_], 0, 0, 0);     \
                acc[rt_][nt_] = __builtin_amdgcn_mfma_f32_16x16x32_f16(        \
                    af[rt_][1], CB[ntl_ * 2 + 1], acc[rt_][nt_], 0, 0, 0);     \
            }                                                                  \
    }
#define STEP(i_, CUR, NXT) { PREFH(NXT, (i_) + 1); COMPUTEH(CUR, i_); }

    PREFH(WA, 0);
    STEP(0, WA, WB);  STEP(1, WB, WA);  STEP(2, WA, WB);  STEP(3, WB, WA);
    STEP(4, WA, WB);  STEP(5, WB, WA);  STEP(6, WA, WB);  STEP(7, WB, WA);
    STEP(8, WA, WB);  STEP(9, WB, WA);  STEP(10, WA, WB); STEP(11, WB, WA);
    STEP(12, WA, WB); STEP(13, WB, WA); STEP(14, WA, WB);
    COMPUTEH(WB, 15);
#undef PREFH
#undef COMPUTEH
#undef STEP

    // ---- epilogue: ah!=0 waves dump f16 partials (lane-contiguous),
    //      one barrier, ah==0 waves combine + residual + LayerNorm ----
    if (ah != 0) {
        const int q = rg * 7 + (ah - 1);     // 0..13
        #pragma unroll
        for (int rt = 0; rt < 2; ++rt)
            #pragma unroll
            for (int nt = 0; nt < 4; ++nt) {
                int base = (((q * 2 + rt) * 4 + nt) * 2) * 64 + l;
                half2v p01 = { (_Float16)acc[rt][nt][0], (_Float16)acc[rt][nt][1] };
                half2v p23 = { (_Float16)acc[rt][nt][2], (_Float16)acc[rt][nt][3] };
                Pf[base] = p01;
                Pf[base + 64] = p23;
            }
    }
    __syncthreads();

    if (ah == 0) {
        float gba[4], bta[4];
        #pragma unroll
        for (int nt = 0; nt < 4; ++nt) {
            gba[nt] = gamma[nt * 16 + lr];
            bta[nt] = beta[nt * 16 + lr];
        }
        #pragma unroll
        for (int rt = 0; rt < 2; ++rt) {
            float rv[4][4], sum[4], ssq[4];
            #pragma unroll
            for (int nt = 0; nt < 4; ++nt) {
                float v0 = acc[rt][nt][0], v1 = acc[rt][nt][1];
                float v2 = acc[rt][nt][2], v3 = acc[rt][nt][3];
                #pragma unroll
                for (int ph = 0; ph < 7; ++ph) {
                    int q = rg * 7 + ph;
                    int base = (((q * 2 + rt) * 4 + nt) * 2) * 64 + l;
                    half2v q01 = Pf[base];
                    half2v q23 = Pf[base + 64];
                    v0 += (float)q01[0]; v1 += (float)q01[1];
                    v2 += (float)q23[0]; v3 += (float)q23[1];
                }
                acc[rt][nt][0] = v0; acc[rt][nt][1] = v1;
                acc[rt][nt][2] = v2; acc[rt][nt][3] = v3;
            }
            #pragma unroll
            for (int reg = 0; reg < 4; ++reg) {
                const int row_l = rt * 16 + lg * 4 + reg;
                const float* xr = x + (size_t)(rbase + row_l) * 64;
                float s_ = 0.f, q_ = 0.f;
                #pragma unroll
                for (int nt = 0; nt < 4; ++nt) {
                    float v = acc[rt][nt][reg] + xr[nt * 16 + lr];
                    rv[nt][reg] = v;
                    s_ += v;
                    q_ += v * v;
                }
                sum[reg] = s_;
                ssq[reg] = q_;
            }
            #pragma unroll
            for (int m = 1; m < 16; m <<= 1) {
                #pragma unroll
                for (int reg = 0; reg < 4; ++reg) {
                    sum[reg] += __shfl_xor(sum[reg], m, 64);
                    ssq[reg] += __shfl_xor(ssq[reg], m, 64);
                }
            }
            #pragma unroll
            for (int reg = 0; reg < 4; ++reg) {
                float mean = sum[reg] * (1.f / 64.f);
                float var = ssq[reg] * (1.f / 64.f) - mean * mean;
                float rstd = __frsqrt_rn(var + LN_EPS);
                const int gr = rbase + rt * 16 + lg * 4 + reg;
                #pragma unroll
                for (int nt = 0; nt < 4; ++nt) {
                    float y = (rv[nt][reg] - mean) * rstd * gba[nt] + bta[nt];
                    out[(size_t)gr * 64 + nt * 16 + lr] = y;
                }
            }
        }
    }
}

// ---------------------------------------------------------------------------
extern "C" void kernel_launch(void* const* d_in, const int* in_sizes, int n_in,
                              void* d_out, int out_size, void* d_ws, size_t ws_size,
                              hipStream_t stream) {
    const float* x     = (const float*)d_in[0];
    const float* W     = (const float*)d_in[1];
    const float* gamma = (const float*)d_in[2];
    const float* beta  = (const float*)d_in[3];
    float* outp        = (float*)d_out;

    char* ws = (char*)d_ws;
    _Float16* s_f16 = (_Float16*)ws;                                    // 4 MB
    _Float16* wt2   = (_Float16*)(ws + (size_t)B_DIM * S_DIM * 64 * 2); // 512 KB

    prep_stage1<<<1536, 256, 0, stream>>>(x, W, wt2, s_f16);
    stage2<<<(B_DIM * S_DIM) / 64, 1024, 0, stream>>>(x, s_f16, wt2, gamma, beta, outp);
}